// Round 6
// baseline (122.264 us; speedup 1.0000x reference)
//
#include <hip/hip_runtime.h>

// VQ color lookup, round 5.
// R4 post-mortem: DS is ~20 µs, but VALUBusy*dur ≈ 50 µs vs a 24 µs static
// count -> ~2x codegen overhead from six separate 1-instr asm statements
// (register-copy glue + unschedulable 8-deep chains). Fix: ONE 32-instr asm
// block per palette pair covering all 4 pixels, hand-interleaved round-robin
// (dep distance 4 instrs), early-clobber operands -> no copies, no stalls.
// Numerics bit-identical to numpy ref (contract off, left-assoc,
// 2*cross == cr+cr exact): R1-R4 all passed with absmax 0.0.

#define KPAL 512
#define HW   65536            // 256*256
#define CHW  (3 * HW)
#define NPIX (8 * HW)         // 524288 pixels
#define NELEM (NPIX * 3)      // 1572864 output color elements
#define PPT  4                // pixels per thread

typedef float f2 __attribute__((ext_vector_type(2)));

struct __align__(32) Pair {   // palette entries 2j (lo half) and 2j+1 (hi)
    f2 x, y, z, w;            // w = ||t||^2 (contract-off)
};

__global__ __launch_bounds__(256)
void vq_kernel(const float* __restrict__ z,
               const float* __restrict__ table,
               float* __restrict__ out,
               float* __restrict__ loss)
{
    __shared__ Pair stab[KPAL / 2];   // 256 pairs, 8 KB
    const int t = threadIdx.x;

    // Stage palette pairs into LDS (one pair per thread, one-time cost).
    {
        const int j = t;
        const float a0 = table[6 * j + 0], a1 = table[6 * j + 1], a2 = table[6 * j + 2];
        const float b0 = table[6 * j + 3], b1 = table[6 * j + 4], b2 = table[6 * j + 5];
        float aw, bw;
        {
#pragma clang fp contract(off)
            aw = a0 * a0 + a1 * a1 + a2 * a2;
            bw = b0 * b0 + b1 * b1 + b2 * b2;
        }
        Pair p;
        p.x = (f2){a0, b0};
        p.y = (f2){a1, b1};
        p.z = (f2){a2, b2};
        p.w = (f2){aw, bw};
        stab[j] = p;
    }
    __syncthreads();

    // P=4 pixels per thread: pixel i at base0 + 256*i (coalesced).
    const int blockbase = blockIdx.x * (256 * PPT);
    const int b  = blockbase >> 16;            // uniform: blocks never straddle
    const int p0 = blockbase & (HW - 1);
    const int base0 = b * CHW + p0 + t;

    float z0[PPT], z1[PPT], z2[PPT];
    f2 Z0[PPT], Z1[PPT], Z2[PPT], ZS[PPT];
#pragma unroll
    for (int i = 0; i < PPT; ++i) {
        const int base = base0 + 256 * i;
        z0[i] = z[base];
        z1[i] = z[base + HW];
        z2[i] = z[base + 2 * HW];
        float zs;
        {
#pragma clang fp contract(off)
            zs = z0[i] * z0[i] + z1[i] * z1[i] + z2[i] * z2[i];
        }
        Z0[i] = (f2){z0[i], z0[i]};
        Z1[i] = (f2){z1[i], z1[i]};
        Z2[i] = (f2){z2[i], z2[i]};
        ZS[i] = (f2){zs, zs};
    }

    float best[PPT];
    int   bi[PPT];
#pragma unroll
    for (int i = 0; i < PPT; ++i) { best[i] = 3.4e38f; bi[i] = 0; }

#pragma unroll 2
    for (int j = 0; j < KPAL / 2; ++j) {
        const Pair c = stab[j];                 // 2x ds_read_b128 broadcast
        f2 d0, d1, d2, d3, t0, t1, t2, t3;
        // One block, round-robin over pixels; dep distance = 4 instrs.
        // Order per pixel: d=z0*cx; t=z1*cy; d+=t; t=z2*cz; d+=t (cross);
        // d+=d (2*cross); d=ZS-d; d+=t2.  Left-assoc == numpy.
        asm("v_pk_mul_f32 %[d0], %[Z00], %[cx]\n\t"
            "v_pk_mul_f32 %[d1], %[Z01], %[cx]\n\t"
            "v_pk_mul_f32 %[d2], %[Z02], %[cx]\n\t"
            "v_pk_mul_f32 %[d3], %[Z03], %[cx]\n\t"
            "v_pk_mul_f32 %[t0], %[Z10], %[cy]\n\t"
            "v_pk_mul_f32 %[t1], %[Z11], %[cy]\n\t"
            "v_pk_mul_f32 %[t2], %[Z12], %[cy]\n\t"
            "v_pk_mul_f32 %[t3], %[Z13], %[cy]\n\t"
            "v_pk_add_f32 %[d0], %[d0], %[t0]\n\t"
            "v_pk_add_f32 %[d1], %[d1], %[t1]\n\t"
            "v_pk_add_f32 %[d2], %[d2], %[t2]\n\t"
            "v_pk_add_f32 %[d3], %[d3], %[t3]\n\t"
            "v_pk_mul_f32 %[t0], %[Z20], %[cz]\n\t"
            "v_pk_mul_f32 %[t1], %[Z21], %[cz]\n\t"
            "v_pk_mul_f32 %[t2], %[Z22], %[cz]\n\t"
            "v_pk_mul_f32 %[t3], %[Z23], %[cz]\n\t"
            "v_pk_add_f32 %[d0], %[d0], %[t0]\n\t"
            "v_pk_add_f32 %[d1], %[d1], %[t1]\n\t"
            "v_pk_add_f32 %[d2], %[d2], %[t2]\n\t"
            "v_pk_add_f32 %[d3], %[d3], %[t3]\n\t"
            "v_pk_add_f32 %[d0], %[d0], %[d0]\n\t"
            "v_pk_add_f32 %[d1], %[d1], %[d1]\n\t"
            "v_pk_add_f32 %[d2], %[d2], %[d2]\n\t"
            "v_pk_add_f32 %[d3], %[d3], %[d3]\n\t"
            "v_pk_add_f32 %[d0], %[S0], %[d0] neg_lo:[0,1] neg_hi:[0,1]\n\t"
            "v_pk_add_f32 %[d1], %[S1], %[d1] neg_lo:[0,1] neg_hi:[0,1]\n\t"
            "v_pk_add_f32 %[d2], %[S2], %[d2] neg_lo:[0,1] neg_hi:[0,1]\n\t"
            "v_pk_add_f32 %[d3], %[S3], %[d3] neg_lo:[0,1] neg_hi:[0,1]\n\t"
            "v_pk_add_f32 %[d0], %[d0], %[cw]\n\t"
            "v_pk_add_f32 %[d1], %[d1], %[cw]\n\t"
            "v_pk_add_f32 %[d2], %[d2], %[cw]\n\t"
            "v_pk_add_f32 %[d3], %[d3], %[cw]"
            : [d0] "=&v"(d0), [d1] "=&v"(d1), [d2] "=&v"(d2), [d3] "=&v"(d3),
              [t0] "=&v"(t0), [t1] "=&v"(t1), [t2] "=&v"(t2), [t3] "=&v"(t3)
            : [Z00] "v"(Z0[0]), [Z01] "v"(Z0[1]), [Z02] "v"(Z0[2]), [Z03] "v"(Z0[3]),
              [Z10] "v"(Z1[0]), [Z11] "v"(Z1[1]), [Z12] "v"(Z1[2]), [Z13] "v"(Z1[3]),
              [Z20] "v"(Z2[0]), [Z21] "v"(Z2[1]), [Z22] "v"(Z2[2]), [Z23] "v"(Z2[3]),
              [S0] "v"(ZS[0]), [S1] "v"(ZS[1]), [S2] "v"(ZS[2]), [S3] "v"(ZS[3]),
              [cx] "v"(c.x), [cy] "v"(c.y), [cz] "v"(c.z), [cw] "v"(c.w));

        const int k0 = 2 * j, k1 = 2 * j + 1;
        if (d0.x < best[0]) { best[0] = d0.x; bi[0] = k0; }
        if (d0.y < best[0]) { best[0] = d0.y; bi[0] = k1; }
        if (d1.x < best[1]) { best[1] = d1.x; bi[1] = k0; }
        if (d1.y < best[1]) { best[1] = d1.y; bi[1] = k1; }
        if (d2.x < best[2]) { best[2] = d2.x; bi[2] = k0; }
        if (d2.y < best[2]) { best[2] = d2.y; bi[2] = k1; }
        if (d3.x < best[3]) { best[3] = d3.x; bi[3] = k0; }
        if (d3.y < best[3]) { best[3] = d3.y; bi[3] = k1; }
    }

    float lsum = 0.0f;
#pragma unroll
    for (int i = 0; i < PPT; ++i) {
        const int base = base0 + 256 * i;
        const float c0 = table[3 * bi[i] + 0];   // divergent, L1-hot 6 KB
        const float c1 = table[3 * bi[i] + 1];
        const float c2 = table[3 * bi[i] + 2];
        out[base]          = c0;
        out[base + HW]     = c1;
        out[base + 2 * HW] = c2;
        const float e0 = c0 - z0[i], e1 = c1 - z1[i], e2 = c2 - z2[i];
        lsum += e0 * e0 + e1 * e1 + e2 * e2;
    }

    for (int off = 32; off > 0; off >>= 1)
        lsum += __shfl_down(lsum, off);

    __shared__ float wsum[4];
    const int wid = t >> 6;
    if ((t & 63) == 0) wsum[wid] = lsum;
    __syncthreads();
    if (t == 0) {
        const float s = wsum[0] + wsum[1] + wsum[2] + wsum[3];
        atomicAdd(loss, s * (11.0f / (float)NELEM));
    }
}

extern "C" void kernel_launch(void* const* d_in, const int* in_sizes, int n_in,
                              void* d_out, int out_size, void* d_ws, size_t ws_size,
                              hipStream_t stream)
{
    const float* z     = (const float*)d_in[0];
    const float* table = (const float*)d_in[1];
    float* out  = (float*)d_out;
    float* loss = out + NELEM;

    hipMemsetAsync(loss, 0, sizeof(float), stream);
    vq_kernel<<<NPIX / (256 * PPT), 256, 0, stream>>>(z, table, out, loss);
}

// Round 8
// 118.521 us; speedup vs baseline: 1.0316x; 1.0316x over previous
//
#include <hip/hip_runtime.h>

// VQ color lookup, round 6 (resubmit — R7 bench was an infra failure).
// R5 established: v_pk_*_f32 executes at 4 cyc/wave64 (same FLOP rate as
// scalar) -> the kernel is VALU-EXECUTION bound; only fewer ops help.
// Exact-arithmetic reductions (both preserve numpy bit-identity):
//  1) halving: compare d2/2. hz=0.5*z2s, ht2=0.5*t2 exact; RN commutes with
//     *0.5 -> RN(RN(hz-cross)+ht2) == numpy_d2/2 bit-exact. Saves 2*cross.
//  2) min3 + deferred index: per pair, imp=(dx<b)|(dy<b); bj=imp?j:bj;
//     b=min3(b,dx,dy). First-index tie-break recovered post-loop by exact
//     recompute of pair bj's lo distance and dx==best test (the global min
//     first occurs in pair bj, so earlier pairs are strictly greater).
// 28 pk + ~16 select VALU per pair per wave ≈ 31 µs execution floor.
// R1-R5 all passed absmax 0.0 with this op ordering.

#define KPAL 512
#define HW   65536            // 256*256
#define CHW  (3 * HW)
#define NPIX (8 * HW)         // 524288 pixels
#define NELEM (NPIX * 3)      // 1572864 output color elements
#define PPT  4                // pixels per thread

typedef float f2 __attribute__((ext_vector_type(2)));

struct __align__(32) Pair {   // palette entries 2j (lo half) and 2j+1 (hi)
    f2 x, y, z, w;            // w = 0.5 * ||t||^2 (contract-off, exact halve)
};

__global__ __launch_bounds__(256)
void vq_kernel(const float* __restrict__ z,
               const float* __restrict__ table,
               float* __restrict__ out,
               float* __restrict__ loss)
{
    __shared__ Pair stab[KPAL / 2];   // 256 pairs, 8 KB
    const int t = threadIdx.x;

    // Stage palette pairs into LDS (one pair per thread, one-time cost).
    {
        const int j = t;
        const float a0 = table[6 * j + 0], a1 = table[6 * j + 1], a2 = table[6 * j + 2];
        const float b0 = table[6 * j + 3], b1 = table[6 * j + 4], b2 = table[6 * j + 5];
        float aw, bw;
        {
#pragma clang fp contract(off)
            aw = a0 * a0 + a1 * a1 + a2 * a2;
            bw = b0 * b0 + b1 * b1 + b2 * b2;
        }
        Pair p;
        p.x = (f2){a0, b0};
        p.y = (f2){a1, b1};
        p.z = (f2){a2, b2};
        p.w = (f2){0.5f * aw, 0.5f * bw};   // exact
        stab[j] = p;
    }
    __syncthreads();

    // P=4 pixels per thread: pixel i at base0 + 256*i (coalesced).
    const int blockbase = blockIdx.x * (256 * PPT);
    const int b  = blockbase >> 16;            // uniform: blocks never straddle
    const int p0 = blockbase & (HW - 1);
    const int base0 = b * CHW + p0 + t;

    float z0[PPT], z1[PPT], z2[PPT], hz[PPT];
    f2 Z0[PPT], Z1[PPT], Z2[PPT], HZ[PPT];
#pragma unroll
    for (int i = 0; i < PPT; ++i) {
        const int base = base0 + 256 * i;
        z0[i] = z[base];
        z1[i] = z[base + HW];
        z2[i] = z[base + 2 * HW];
        float zs;
        {
#pragma clang fp contract(off)
            zs = z0[i] * z0[i] + z1[i] * z1[i] + z2[i] * z2[i];
        }
        hz[i] = 0.5f * zs;                     // exact
        Z0[i] = (f2){z0[i], z0[i]};
        Z1[i] = (f2){z1[i], z1[i]};
        Z2[i] = (f2){z2[i], z2[i]};
        HZ[i] = (f2){hz[i], hz[i]};
    }

    float best[PPT];
    int   bj[PPT];
#pragma unroll
    for (int i = 0; i < PPT; ++i) { best[i] = 3.4e38f; bj[i] = 0; }

#pragma unroll 2
    for (int j = 0; j < KPAL / 2; ++j) {
        const Pair c = stab[j];                 // 2x ds_read_b128 broadcast
        f2 d0, d1, d2, d3, t0, t1, t2, t3;
        // Per px (lo/hi lanes = entries 2j / 2j+1), left-assoc == numpy/2:
        //   d=z0*cx; t=z1*cy; d+=t; t=z2*cz; d+=t (cross); d=hz-d; d+=ht2.
        asm("v_pk_mul_f32 %[d0], %[Z00], %[cx]\n\t"
            "v_pk_mul_f32 %[d1], %[Z01], %[cx]\n\t"
            "v_pk_mul_f32 %[d2], %[Z02], %[cx]\n\t"
            "v_pk_mul_f32 %[d3], %[Z03], %[cx]\n\t"
            "v_pk_mul_f32 %[t0], %[Z10], %[cy]\n\t"
            "v_pk_mul_f32 %[t1], %[Z11], %[cy]\n\t"
            "v_pk_mul_f32 %[t2], %[Z12], %[cy]\n\t"
            "v_pk_mul_f32 %[t3], %[Z13], %[cy]\n\t"
            "v_pk_add_f32 %[d0], %[d0], %[t0]\n\t"
            "v_pk_add_f32 %[d1], %[d1], %[t1]\n\t"
            "v_pk_add_f32 %[d2], %[d2], %[t2]\n\t"
            "v_pk_add_f32 %[d3], %[d3], %[t3]\n\t"
            "v_pk_mul_f32 %[t0], %[Z20], %[cz]\n\t"
            "v_pk_mul_f32 %[t1], %[Z21], %[cz]\n\t"
            "v_pk_mul_f32 %[t2], %[Z22], %[cz]\n\t"
            "v_pk_mul_f32 %[t3], %[Z23], %[cz]\n\t"
            "v_pk_add_f32 %[d0], %[d0], %[t0]\n\t"
            "v_pk_add_f32 %[d1], %[d1], %[t1]\n\t"
            "v_pk_add_f32 %[d2], %[d2], %[t2]\n\t"
            "v_pk_add_f32 %[d3], %[d3], %[t3]\n\t"
            "v_pk_add_f32 %[d0], %[H0], %[d0] neg_lo:[0,1] neg_hi:[0,1]\n\t"
            "v_pk_add_f32 %[d1], %[H1], %[d1] neg_lo:[0,1] neg_hi:[0,1]\n\t"
            "v_pk_add_f32 %[d2], %[H2], %[d2] neg_lo:[0,1] neg_hi:[0,1]\n\t"
            "v_pk_add_f32 %[d3], %[H3], %[d3] neg_lo:[0,1] neg_hi:[0,1]\n\t"
            "v_pk_add_f32 %[d0], %[d0], %[cw]\n\t"
            "v_pk_add_f32 %[d1], %[d1], %[cw]\n\t"
            "v_pk_add_f32 %[d2], %[d2], %[cw]\n\t"
            "v_pk_add_f32 %[d3], %[d3], %[cw]"
            : [d0] "=&v"(d0), [d1] "=&v"(d1), [d2] "=&v"(d2), [d3] "=&v"(d3),
              [t0] "=&v"(t0), [t1] "=&v"(t1), [t2] "=&v"(t2), [t3] "=&v"(t3)
            : [Z00] "v"(Z0[0]), [Z01] "v"(Z0[1]), [Z02] "v"(Z0[2]), [Z03] "v"(Z0[3]),
              [Z10] "v"(Z1[0]), [Z11] "v"(Z1[1]), [Z12] "v"(Z1[2]), [Z13] "v"(Z1[3]),
              [Z20] "v"(Z2[0]), [Z21] "v"(Z2[1]), [Z22] "v"(Z2[2]), [Z23] "v"(Z2[3]),
              [H0] "v"(HZ[0]), [H1] "v"(HZ[1]), [H2] "v"(HZ[2]), [H3] "v"(HZ[3]),
              [cx] "v"(c.x), [cy] "v"(c.y), [cz] "v"(c.z), [cw] "v"(c.w));

        f2 dd[PPT] = {d0, d1, d2, d3};
#pragma unroll
        for (int i = 0; i < PPT; ++i) {
            const bool imp = (dd[i].x < best[i]) | (dd[i].y < best[i]);
            bj[i] = imp ? j : bj[i];
            best[i] = fminf(fminf(best[i], dd[i].x), dd[i].y);  // -> v_min3
        }
    }

    // Resolve lo/hi within the winning pair (exact recompute of lo entry).
    int bi[PPT];
#pragma unroll
    for (int i = 0; i < PPT; ++i) {
        const Pair cc = stab[bj[i]];           // divergent, one-time
        float dx;
        {
#pragma clang fp contract(off)
            float m = z0[i] * cc.x.x;
            m = m + z1[i] * cc.y.x;
            m = m + z2[i] * cc.z.x;
            float s = hz[i] - m;
            dx = s + cc.w.x;
        }
        bi[i] = (dx == best[i]) ? 2 * bj[i] : 2 * bj[i] + 1;
    }

    float lsum = 0.0f;
#pragma unroll
    for (int i = 0; i < PPT; ++i) {
        const int base = base0 + 256 * i;
        const float c0 = table[3 * bi[i] + 0];   // divergent, L1-hot 6 KB
        const float c1 = table[3 * bi[i] + 1];
        const float c2 = table[3 * bi[i] + 2];
        out[base]          = c0;
        out[base + HW]     = c1;
        out[base + 2 * HW] = c2;
        const float e0 = c0 - z0[i], e1 = c1 - z1[i], e2 = c2 - z2[i];
        lsum += e0 * e0 + e1 * e1 + e2 * e2;
    }

    for (int off = 32; off > 0; off >>= 1)
        lsum += __shfl_down(lsum, off);

    __shared__ float wsum[4];
    const int wid = t >> 6;
    if ((t & 63) == 0) wsum[wid] = lsum;
    __syncthreads();
    if (t == 0) {
        const float s = wsum[0] + wsum[1] + wsum[2] + wsum[3];
        atomicAdd(loss, s * (11.0f / (float)NELEM));
    }
}

extern "C" void kernel_launch(void* const* d_in, const int* in_sizes, int n_in,
                              void* d_out, int out_size, void* d_ws, size_t ws_size,
                              hipStream_t stream)
{
    const float* z     = (const float*)d_in[0];
    const float* table = (const float*)d_in[1];
    float* out  = (float*)d_out;
    float* loss = out + NELEM;

    hipMemsetAsync(loss, 0, sizeof(float), stream);
    vq_kernel<<<NPIX / (256 * PPT), 256, 0, stream>>>(z, table, out, loss);
}

// Round 9
// 112.927 us; speedup vs baseline: 1.0827x; 1.0495x over previous
//
#include <hip/hip_runtime.h>

// VQ color lookup, round 7: split-K over the palette.
// R6 was latency-bound: 2 waves/SIMD couldn't hide ds_read latency (~120cyc)
// ahead of each pair's compute; VALU floor ~31 µs vs 69 µs measured.
// New structure: block = 512 px, 4 waves; wave w scans palette quarter
// [w*128, w*128+128) for ALL 512 px (PPT=8), partial (best,k) combined via
// LDS with an ordered strict-< scan (tie -> lowest quarter = lowest k ==
// numpy first-index). 1024 blocks -> 16 waves/CU (4/SIMD, 2x TLP); per-wave
// DS is quartered. VOP3P op_sel broadcasts halve the Z register footprint:
// ZA=(z0,z1), ZB=(z2,hz) one VGPR pair each.
// Per-entry arithmetic identical to R6 (halved distance, contract-off,
// left-assoc) -> bit-identical to numpy. R1-R6 all passed absmax 0.0.

#define KPAL 512
#define HW   65536            // 256*256
#define CHW  (3 * HW)
#define NPIX (8 * HW)         // 524288 pixels
#define NELEM (NPIX * 3)      // 1572864 output color elements
#define PPT   8               // pixels per thread (64 lanes * 8 = 512 px/block)
#define NWAVE 4
#define PAIRS_PER_WAVE (KPAL / 2 / NWAVE)   // 64

typedef float f2 __attribute__((ext_vector_type(2)));

struct __align__(32) Pair {   // palette entries 2j (lo half) and 2j+1 (hi)
    f2 x, y, z, w;            // w = 0.5 * ||t||^2 (contract-off, exact halve)
};

// 4 pixels x 1 palette pair, halved distance, numpy-exact order:
//   d = z0*cx; d += z1*cy; d += z2*cz (cross); d = hz - d; d += ht2
// ZA = (z0, z1), ZB = (z2, hz); op_sel broadcasts the needed half.
static __device__ __forceinline__ void quad_dist(
    f2 cx, f2 cy, f2 cz, f2 cw,
    f2 A0, f2 B0, f2 A1, f2 B1, f2 A2, f2 B2, f2 A3, f2 B3,
    f2& r0, f2& r1, f2& r2, f2& r3)
{
    f2 d0, d1, d2, d3, t0, t1, t2, t3;
    asm("v_pk_mul_f32 %[d0], %[A0], %[cx] op_sel:[0,0] op_sel_hi:[0,1]\n\t"
        "v_pk_mul_f32 %[d1], %[A1], %[cx] op_sel:[0,0] op_sel_hi:[0,1]\n\t"
        "v_pk_mul_f32 %[d2], %[A2], %[cx] op_sel:[0,0] op_sel_hi:[0,1]\n\t"
        "v_pk_mul_f32 %[d3], %[A3], %[cx] op_sel:[0,0] op_sel_hi:[0,1]\n\t"
        "v_pk_mul_f32 %[t0], %[A0], %[cy] op_sel:[1,0] op_sel_hi:[1,1]\n\t"
        "v_pk_mul_f32 %[t1], %[A1], %[cy] op_sel:[1,0] op_sel_hi:[1,1]\n\t"
        "v_pk_mul_f32 %[t2], %[A2], %[cy] op_sel:[1,0] op_sel_hi:[1,1]\n\t"
        "v_pk_mul_f32 %[t3], %[A3], %[cy] op_sel:[1,0] op_sel_hi:[1,1]\n\t"
        "v_pk_add_f32 %[d0], %[d0], %[t0]\n\t"
        "v_pk_add_f32 %[d1], %[d1], %[t1]\n\t"
        "v_pk_add_f32 %[d2], %[d2], %[t2]\n\t"
        "v_pk_add_f32 %[d3], %[d3], %[t3]\n\t"
        "v_pk_mul_f32 %[t0], %[B0], %[cz] op_sel:[0,0] op_sel_hi:[0,1]\n\t"
        "v_pk_mul_f32 %[t1], %[B1], %[cz] op_sel:[0,0] op_sel_hi:[0,1]\n\t"
        "v_pk_mul_f32 %[t2], %[B2], %[cz] op_sel:[0,0] op_sel_hi:[0,1]\n\t"
        "v_pk_mul_f32 %[t3], %[B3], %[cz] op_sel:[0,0] op_sel_hi:[0,1]\n\t"
        "v_pk_add_f32 %[d0], %[d0], %[t0]\n\t"
        "v_pk_add_f32 %[d1], %[d1], %[t1]\n\t"
        "v_pk_add_f32 %[d2], %[d2], %[t2]\n\t"
        "v_pk_add_f32 %[d3], %[d3], %[t3]\n\t"
        "v_pk_add_f32 %[d0], %[B0], %[d0] op_sel:[1,0] op_sel_hi:[1,1] neg_lo:[0,1] neg_hi:[0,1]\n\t"
        "v_pk_add_f32 %[d1], %[B1], %[d1] op_sel:[1,0] op_sel_hi:[1,1] neg_lo:[0,1] neg_hi:[0,1]\n\t"
        "v_pk_add_f32 %[d2], %[B2], %[d2] op_sel:[1,0] op_sel_hi:[1,1] neg_lo:[0,1] neg_hi:[0,1]\n\t"
        "v_pk_add_f32 %[d3], %[B3], %[d3] op_sel:[1,0] op_sel_hi:[1,1] neg_lo:[0,1] neg_hi:[0,1]\n\t"
        "v_pk_add_f32 %[d0], %[d0], %[cw]\n\t"
        "v_pk_add_f32 %[d1], %[d1], %[cw]\n\t"
        "v_pk_add_f32 %[d2], %[d2], %[cw]\n\t"
        "v_pk_add_f32 %[d3], %[d3], %[cw]"
        : [d0] "=&v"(d0), [d1] "=&v"(d1), [d2] "=&v"(d2), [d3] "=&v"(d3),
          [t0] "=&v"(t0), [t1] "=&v"(t1), [t2] "=&v"(t2), [t3] "=&v"(t3)
        : [A0] "v"(A0), [B0] "v"(B0), [A1] "v"(A1), [B1] "v"(B1),
          [A2] "v"(A2), [B2] "v"(B2), [A3] "v"(A3), [B3] "v"(B3),
          [cx] "v"(cx), [cy] "v"(cy), [cz] "v"(cz), [cw] "v"(cw));
    r0 = d0; r1 = d1; r2 = d2; r3 = d3;
}

__global__ __launch_bounds__(256, 4)
void vq_kernel(const float* __restrict__ z,
               const float* __restrict__ table,
               float* __restrict__ out,
               float* __restrict__ loss)
{
    __shared__ Pair  stab[KPAL / 2];        // 8 KB
    __shared__ float cb_best[NWAVE][512];   // 8 KB
    __shared__ int   cb_bi[NWAVE][512];     // 8 KB
    const int t = threadIdx.x;
    const int w = t >> 6, lane = t & 63;

    // Stage palette pairs into LDS.
    {
        const int j = t;
        const float a0 = table[6 * j + 0], a1 = table[6 * j + 1], a2 = table[6 * j + 2];
        const float b0 = table[6 * j + 3], b1 = table[6 * j + 4], b2 = table[6 * j + 5];
        float aw, bw;
        {
#pragma clang fp contract(off)
            aw = a0 * a0 + a1 * a1 + a2 * a2;
            bw = b0 * b0 + b1 * b1 + b2 * b2;
        }
        Pair p;
        p.x = (f2){a0, b0};
        p.y = (f2){a1, b1};
        p.z = (f2){a2, b2};
        p.w = (f2){0.5f * aw, 0.5f * bw};   // exact
        stab[j] = p;
    }
    __syncthreads();

    // Block covers 512 consecutive pixels; all 4 waves process the same px.
    const int blockbase = blockIdx.x * 512;
    const int b  = blockbase >> 16;           // blocks never straddle batch
    const int p0 = blockbase & (HW - 1);
    const int base0 = b * CHW + p0 + lane;    // pixel i at base0 + 64*i

    f2 ZA[PPT], ZB[PPT];                      // (z0,z1), (z2, 0.5*||z||^2)
#pragma unroll
    for (int i = 0; i < PPT; ++i) {
        const int base = base0 + 64 * i;
        const float z0 = z[base];
        const float z1 = z[base + HW];
        const float z2 = z[base + 2 * HW];
        float zs;
        {
#pragma clang fp contract(off)
            zs = z0 * z0 + z1 * z1 + z2 * z2;
        }
        ZA[i] = (f2){z0, z1};
        ZB[i] = (f2){z2, 0.5f * zs};          // exact halve
    }

    float best[PPT];
    int   bj[PPT];                            // global pair index
#pragma unroll
    for (int i = 0; i < PPT; ++i) { best[i] = 3.4e38f; bj[i] = w * PAIRS_PER_WAVE; }

    // Wave w scans its palette quarter for all 8 px.
#pragma unroll 2
    for (int jj = 0; jj < PAIRS_PER_WAVE; ++jj) {
        const int jg = w * PAIRS_PER_WAVE + jj;
        const Pair c = stab[jg];              // uniform -> ds broadcast
        f2 r[PPT];
        quad_dist(c.x, c.y, c.z, c.w,
                  ZA[0], ZB[0], ZA[1], ZB[1], ZA[2], ZB[2], ZA[3], ZB[3],
                  r[0], r[1], r[2], r[3]);
        quad_dist(c.x, c.y, c.z, c.w,
                  ZA[4], ZB[4], ZA[5], ZB[5], ZA[6], ZB[6], ZA[7], ZB[7],
                  r[4], r[5], r[6], r[7]);
#pragma unroll
        for (int i = 0; i < PPT; ++i) {
            const bool imp = (r[i].x < best[i]) | (r[i].y < best[i]);
            bj[i] = imp ? jg : bj[i];
            best[i] = fminf(fminf(best[i], r[i].x), r[i].y);  // v_min3
        }
    }

    // Resolve lo/hi within the winning pair (exact lo recompute), publish.
#pragma unroll
    for (int i = 0; i < PPT; ++i) {
        const Pair cc = stab[bj[i]];
        float dx;
        {
#pragma clang fp contract(off)
            float m = ZA[i].x * cc.x.x;       // z0*cx
            m = m + ZA[i].y * cc.y.x;         // + z1*cy
            m = m + ZB[i].x * cc.z.x;         // + z2*cz
            float s = ZB[i].y - m;            // hz - cross
            dx = s + cc.w.x;                  // + ht2
        }
        const int bi = (dx == best[i]) ? 2 * bj[i] : 2 * bj[i] + 1;
        cb_best[w][lane + 64 * i] = best[i];
        cb_bi[w][lane + 64 * i]   = bi;
    }
    __syncthreads();

    // Combine quarters (ordered strict < : tie -> lowest quarter = lowest k),
    // write output, accumulate loss. Each thread finalizes 2 pixels.
    float lsum = 0.0f;
#pragma unroll
    for (int rI = 0; rI < 2; ++rI) {
        const int p = t + 256 * rI;           // 0..511 within block
        float bb = cb_best[0][p];
        int   kk = cb_bi[0][p];
#pragma unroll
        for (int ww = 1; ww < NWAVE; ++ww) {
            const float d = cb_best[ww][p];
            const int   k2 = cb_bi[ww][p];
            if (d < bb) { bb = d; kk = k2; }
        }
        const int base = b * CHW + p0 + p;
        const float c0 = table[3 * kk + 0];
        const float c1 = table[3 * kk + 1];
        const float c2 = table[3 * kk + 2];
        out[base]          = c0;
        out[base + HW]     = c1;
        out[base + 2 * HW] = c2;
        const float z0 = z[base], z1 = z[base + HW], z2 = z[base + 2 * HW];
        const float e0 = c0 - z0, e1 = c1 - z1, e2 = c2 - z2;
        lsum += e0 * e0 + e1 * e1 + e2 * e2;
    }

    for (int off = 32; off > 0; off >>= 1)
        lsum += __shfl_down(lsum, off);

    __shared__ float wsum[4];
    if ((t & 63) == 0) wsum[w] = lsum;
    __syncthreads();
    if (t == 0) {
        const float s = wsum[0] + wsum[1] + wsum[2] + wsum[3];
        atomicAdd(loss, s * (11.0f / (float)NELEM));
    }
}

extern "C" void kernel_launch(void* const* d_in, const int* in_sizes, int n_in,
                              void* d_out, int out_size, void* d_ws, size_t ws_size,
                              hipStream_t stream)
{
    const float* z     = (const float*)d_in[0];
    const float* table = (const float*)d_in[1];
    float* out  = (float*)d_out;
    float* loss = out + NELEM;

    hipMemsetAsync(loss, 0, sizeof(float), stream);
    vq_kernel<<<NPIX / 512, 256, 0, stream>>>(z, table, out, loss);
}

// Round 10
// 106.822 us; speedup vs baseline: 1.1446x; 1.0572x over previous
//
#include <hip/hip_runtime.h>

// VQ color lookup, round 8: split-K + full occupancy.
// R7: static VALU 31 µs vs 46 busy + 18 idle; only 4 blocks/CU (LDS 25 KB).
// Changes:
//  - block = 256 px (PPT=4), grid 2048 -> 8 blocks/CU = 32 waves/CU (8/SIMD);
//    LDS 16.4 KB/block; __launch_bounds__(256,8) caps VGPR at 64.
//  - 3-op select: mn = v_min3(best,dx,dy); imp = mn < best; bj = cndmask.
//    Strict-improvement keeps numpy first-index across pairs; in-pair lo/hi
//    resolved post-loop by exact lo recompute (proven R6/R7, absmax 0.0).
// Per-entry arithmetic unchanged (halved distance, contract-off, left-assoc,
// op_sel broadcasts) -> bit-identical to numpy. R1-R7 all absmax 0.0.

#define KPAL 512
#define HW   65536            // 256*256
#define CHW  (3 * HW)
#define NPIX (8 * HW)         // 524288 pixels
#define NELEM (NPIX * 3)      // 1572864 output color elements
#define PPT   4               // pixels per thread (64 lanes * 4 = 256 px/block)
#define NWAVE 4
#define PAIRS_PER_WAVE (KPAL / 2 / NWAVE)   // 64

typedef float f2 __attribute__((ext_vector_type(2)));

struct __align__(32) Pair {   // palette entries 2j (lo half) and 2j+1 (hi)
    f2 x, y, z, w;            // w = 0.5 * ||t||^2 (contract-off, exact halve)
};

// 4 pixels x 1 palette pair, halved distance, numpy-exact order:
//   d = z0*cx; d += z1*cy; d += z2*cz (cross); d = hz - d; d += ht2
// ZA = (z0, z1), ZB = (z2, hz); op_sel broadcasts the needed half.
static __device__ __forceinline__ void quad_dist(
    f2 cx, f2 cy, f2 cz, f2 cw,
    f2 A0, f2 B0, f2 A1, f2 B1, f2 A2, f2 B2, f2 A3, f2 B3,
    f2& r0, f2& r1, f2& r2, f2& r3)
{
    f2 d0, d1, d2, d3, t0, t1, t2, t3;
    asm("v_pk_mul_f32 %[d0], %[A0], %[cx] op_sel:[0,0] op_sel_hi:[0,1]\n\t"
        "v_pk_mul_f32 %[d1], %[A1], %[cx] op_sel:[0,0] op_sel_hi:[0,1]\n\t"
        "v_pk_mul_f32 %[d2], %[A2], %[cx] op_sel:[0,0] op_sel_hi:[0,1]\n\t"
        "v_pk_mul_f32 %[d3], %[A3], %[cx] op_sel:[0,0] op_sel_hi:[0,1]\n\t"
        "v_pk_mul_f32 %[t0], %[A0], %[cy] op_sel:[1,0] op_sel_hi:[1,1]\n\t"
        "v_pk_mul_f32 %[t1], %[A1], %[cy] op_sel:[1,0] op_sel_hi:[1,1]\n\t"
        "v_pk_mul_f32 %[t2], %[A2], %[cy] op_sel:[1,0] op_sel_hi:[1,1]\n\t"
        "v_pk_mul_f32 %[t3], %[A3], %[cy] op_sel:[1,0] op_sel_hi:[1,1]\n\t"
        "v_pk_add_f32 %[d0], %[d0], %[t0]\n\t"
        "v_pk_add_f32 %[d1], %[d1], %[t1]\n\t"
        "v_pk_add_f32 %[d2], %[d2], %[t2]\n\t"
        "v_pk_add_f32 %[d3], %[d3], %[t3]\n\t"
        "v_pk_mul_f32 %[t0], %[B0], %[cz] op_sel:[0,0] op_sel_hi:[0,1]\n\t"
        "v_pk_mul_f32 %[t1], %[B1], %[cz] op_sel:[0,0] op_sel_hi:[0,1]\n\t"
        "v_pk_mul_f32 %[t2], %[B2], %[cz] op_sel:[0,0] op_sel_hi:[0,1]\n\t"
        "v_pk_mul_f32 %[t3], %[B3], %[cz] op_sel:[0,0] op_sel_hi:[0,1]\n\t"
        "v_pk_add_f32 %[d0], %[d0], %[t0]\n\t"
        "v_pk_add_f32 %[d1], %[d1], %[t1]\n\t"
        "v_pk_add_f32 %[d2], %[d2], %[t2]\n\t"
        "v_pk_add_f32 %[d3], %[d3], %[t3]\n\t"
        "v_pk_add_f32 %[d0], %[B0], %[d0] op_sel:[1,0] op_sel_hi:[1,1] neg_lo:[0,1] neg_hi:[0,1]\n\t"
        "v_pk_add_f32 %[d1], %[B1], %[d1] op_sel:[1,0] op_sel_hi:[1,1] neg_lo:[0,1] neg_hi:[0,1]\n\t"
        "v_pk_add_f32 %[d2], %[B2], %[d2] op_sel:[1,0] op_sel_hi:[1,1] neg_lo:[0,1] neg_hi:[0,1]\n\t"
        "v_pk_add_f32 %[d3], %[B3], %[d3] op_sel:[1,0] op_sel_hi:[1,1] neg_lo:[0,1] neg_hi:[0,1]\n\t"
        "v_pk_add_f32 %[d0], %[d0], %[cw]\n\t"
        "v_pk_add_f32 %[d1], %[d1], %[cw]\n\t"
        "v_pk_add_f32 %[d2], %[d2], %[cw]\n\t"
        "v_pk_add_f32 %[d3], %[d3], %[cw]"
        : [d0] "=&v"(d0), [d1] "=&v"(d1), [d2] "=&v"(d2), [d3] "=&v"(d3),
          [t0] "=&v"(t0), [t1] "=&v"(t1), [t2] "=&v"(t2), [t3] "=&v"(t3)
        : [A0] "v"(A0), [B0] "v"(B0), [A1] "v"(A1), [B1] "v"(B1),
          [A2] "v"(A2), [B2] "v"(B2), [A3] "v"(A3), [B3] "v"(B3),
          [cx] "v"(cx), [cy] "v"(cy), [cz] "v"(cz), [cw] "v"(cw));
    r0 = d0; r1 = d1; r2 = d2; r3 = d3;
}

__global__ __launch_bounds__(256, 8)
void vq_kernel(const float* __restrict__ z,
               const float* __restrict__ table,
               float* __restrict__ out,
               float* __restrict__ loss)
{
    __shared__ Pair  stab[KPAL / 2];        // 8 KB
    __shared__ float cb_best[NWAVE][256];   // 4 KB
    __shared__ int   cb_bi[NWAVE][256];     // 4 KB
    const int t = threadIdx.x;
    const int w = t >> 6, lane = t & 63;

    // Stage palette pairs into LDS.
    {
        const int j = t;
        const float a0 = table[6 * j + 0], a1 = table[6 * j + 1], a2 = table[6 * j + 2];
        const float b0 = table[6 * j + 3], b1 = table[6 * j + 4], b2 = table[6 * j + 5];
        float aw, bw;
        {
#pragma clang fp contract(off)
            aw = a0 * a0 + a1 * a1 + a2 * a2;
            bw = b0 * b0 + b1 * b1 + b2 * b2;
        }
        Pair p;
        p.x = (f2){a0, b0};
        p.y = (f2){a1, b1};
        p.z = (f2){a2, b2};
        p.w = (f2){0.5f * aw, 0.5f * bw};   // exact
        stab[j] = p;
    }
    __syncthreads();

    // Block covers 256 consecutive pixels; all 4 waves process the same px.
    const int blockbase = blockIdx.x * 256;
    const int b  = blockbase >> 16;           // blocks never straddle batch
    const int p0 = blockbase & (HW - 1);
    const int base0 = b * CHW + p0 + lane;    // pixel i at base0 + 64*i

    f2 ZA[PPT], ZB[PPT];                      // (z0,z1), (z2, 0.5*||z||^2)
#pragma unroll
    for (int i = 0; i < PPT; ++i) {
        const int base = base0 + 64 * i;
        const float z0 = z[base];
        const float z1 = z[base + HW];
        const float z2 = z[base + 2 * HW];
        float zs;
        {
#pragma clang fp contract(off)
            zs = z0 * z0 + z1 * z1 + z2 * z2;
        }
        ZA[i] = (f2){z0, z1};
        ZB[i] = (f2){z2, 0.5f * zs};          // exact halve
    }

    float best[PPT];
    int   bj[PPT];                            // global pair index
#pragma unroll
    for (int i = 0; i < PPT; ++i) { best[i] = 3.4e38f; bj[i] = w * PAIRS_PER_WAVE; }

    // Wave w scans its palette quarter for all 4 px.
#pragma unroll 2
    for (int jj = 0; jj < PAIRS_PER_WAVE; ++jj) {
        const int jg = w * PAIRS_PER_WAVE + jj;
        const Pair c = stab[jg];              // uniform -> ds broadcast
        f2 r[PPT];
        quad_dist(c.x, c.y, c.z, c.w,
                  ZA[0], ZB[0], ZA[1], ZB[1], ZA[2], ZB[2], ZA[3], ZB[3],
                  r[0], r[1], r[2], r[3]);
#pragma unroll
        for (int i = 0; i < PPT; ++i) {
            const float mn = fminf(fminf(best[i], r[i].x), r[i].y); // v_min3
            const bool imp = mn < best[i];
            bj[i] = imp ? jg : bj[i];
            best[i] = mn;
        }
    }

    // Resolve lo/hi within the winning pair (exact lo recompute), publish.
#pragma unroll
    for (int i = 0; i < PPT; ++i) {
        const Pair cc = stab[bj[i]];
        float dx;
        {
#pragma clang fp contract(off)
            float m = ZA[i].x * cc.x.x;       // z0*cx
            m = m + ZA[i].y * cc.y.x;         // + z1*cy
            m = m + ZB[i].x * cc.z.x;         // + z2*cz
            float s = ZB[i].y - m;            // hz - cross
            dx = s + cc.w.x;                  // + ht2
        }
        const int bi = (dx == best[i]) ? 2 * bj[i] : 2 * bj[i] + 1;
        cb_best[w][lane + 64 * i] = best[i];
        cb_bi[w][lane + 64 * i]   = bi;
    }
    __syncthreads();

    // Combine quarters (ordered strict < : tie -> lowest quarter = lowest k),
    // write output, accumulate loss. One pixel per thread.
    float lsum = 0.0f;
    {
        const int p = t;                      // 0..255 within block
        float bb = cb_best[0][p];
        int   kk = cb_bi[0][p];
#pragma unroll
        for (int ww = 1; ww < NWAVE; ++ww) {
            const float d = cb_best[ww][p];
            const int   k2 = cb_bi[ww][p];
            if (d < bb) { bb = d; kk = k2; }
        }
        const int base = b * CHW + p0 + p;
        const float c0 = table[3 * kk + 0];
        const float c1 = table[3 * kk + 1];
        const float c2 = table[3 * kk + 2];
        out[base]          = c0;
        out[base + HW]     = c1;
        out[base + 2 * HW] = c2;
        const float z0 = z[base], z1 = z[base + HW], z2 = z[base + 2 * HW];
        const float e0 = c0 - z0, e1 = c1 - z1, e2 = c2 - z2;
        lsum += e0 * e0 + e1 * e1 + e2 * e2;
    }

    for (int off = 32; off > 0; off >>= 1)
        lsum += __shfl_down(lsum, off);

    __shared__ float wsum[4];
    if ((t & 63) == 0) wsum[w] = lsum;
    __syncthreads();
    if (t == 0) {
        const float s = wsum[0] + wsum[1] + wsum[2] + wsum[3];
        atomicAdd(loss, s * (11.0f / (float)NELEM));
    }
}

extern "C" void kernel_launch(void* const* d_in, const int* in_sizes, int n_in,
                              void* d_out, int out_size, void* d_ws, size_t ws_size,
                              hipStream_t stream)
{
    const float* z     = (const float*)d_in[0];
    const float* table = (const float*)d_in[1];
    float* out  = (float*)d_out;
    float* loss = out + NELEM;

    hipMemsetAsync(loss, 0, sizeof(float), stream);
    vq_kernel<<<NPIX / 256, 256, 0, stream>>>(z, table, out, loss);
}